// Round 9
// baseline (324.323 us; speedup 1.0000x reference)
//
#include <hip/hip_runtime.h>
#include <stdint.h>

typedef unsigned short u16;
typedef unsigned int u32;
typedef __bf16 bf16_t;
typedef __bf16 bf16x4 __attribute__((ext_vector_type(4)));
typedef __bf16 bf16x8 __attribute__((ext_vector_type(8)));
typedef float f32x4 __attribute__((ext_vector_type(4)));
typedef float f32x16 __attribute__((ext_vector_type(16)));

#define LOG2E 1.4426950408889634f
#define MFMA32(a, b, c) __builtin_amdgcn_mfma_f32_32x32x16_bf16(a, b, c, 0, 0, 0)

__device__ __forceinline__ u16 f2bf(float f) {
    union { float f; unsigned int u; } v; v.f = f;
    unsigned int r = v.u + 0x7fffu + ((v.u >> 16) & 1u);
    return (u16)(r >> 16);
}

__device__ __forceinline__ bf16x8 ld8f_bf(const float* __restrict__ p) {
    float4 a = *reinterpret_cast<const float4*>(p);
    float4 b = *reinterpret_cast<const float4*>(p + 4);
    bf16x8 r;
    r[0] = (bf16_t)a.x; r[1] = (bf16_t)a.y; r[2] = (bf16_t)a.z; r[3] = (bf16_t)a.w;
    r[4] = (bf16_t)b.x; r[5] = (bf16_t)b.y; r[6] = (bf16_t)b.z; r[7] = (bf16_t)b.w;
    return r;
}

__device__ __forceinline__ u32 cvt_pk_bf16(float a, float b) {
    u32 r;
    asm("v_cvt_pk_bf16_f32 %0, %1, %2" : "=v"(r) : "v"(a), "v"(b));
    return r;
}

__device__ __forceinline__ void plane32_swap(u32& a, u32& b) {
    asm("v_permlane32_swap_b32 %0, %1" : "+v"(a), "+v"(b));
}

// Build PV B-operand fragment (16 keys) from 8 consecutive QK C-regs.
__device__ __forceinline__ bf16x8 pack8(const float* p) {
    u32 c0 = cvt_pk_bf16(p[0], p[1]);
    u32 c1 = cvt_pk_bf16(p[2], p[3]);
    u32 c2 = cvt_pk_bf16(p[4], p[5]);
    u32 c3 = cvt_pk_bf16(p[6], p[7]);
    plane32_swap(c0, c2);
    plane32_swap(c1, c3);
    union { u32 u[4]; bf16x8 v; } f;
    f.u[0] = c0; f.u[1] = c1; f.u[2] = c2; f.u[3] = c3;
    return f.v;
}

// async global->LDS, 16B per lane; LDS dest wave-uniform base + lane*16
__device__ __forceinline__ void g2lds16(const u16* g, u16* l) {
    __builtin_amdgcn_global_load_lds(
        (const __attribute__((address_space(1))) unsigned int*)g,
        (__attribute__((address_space(3))) unsigned int*)l, 16, 0, 0);
}

// ---------------------------------------------------------------------------
// Kernel 1: x[B,C,N] fp32 -> xT[B,N,C] bf16, PRE-SWIZZLED per 16B granule:
// row n, granule g stored at granule slot g^(n&7). Blocks >= 2048 convert
// weights to bf16: wqkb = [64 rows (Wq||Wk)][32 granules swizzled g^(n&7)],
// wvb = 8 slices x 1024 granules (slot d holds Wv[d>>2][slice*32+((d&3)^((d>>2)&3))*8..]).
// ---------------------------------------------------------------------------
__global__ __launch_bounds__(256) void k_transpose(
    const float* __restrict__ x,
    const float* __restrict__ Wq, const float* __restrict__ Wk,
    const float* __restrict__ Wv,
    u16* __restrict__ xT, u16* __restrict__ wqkb, u16* __restrict__ wvb) {
    int blk = blockIdx.x;
    int t = threadIdx.x;
    if (blk >= 2048) {
        if (blk == 2048) {          // Wq||Wk -> wqkb (2048 granules)
            for (int j = 0; j < 8; ++j) {
                int fg = j * 256 + t;
                int n = fg >> 5, g = fg & 31;
                const float* src = (n < 32) ? (Wq + (size_t)n * 256 + g * 8)
                                            : (Wk + (size_t)(n - 32) * 256 + g * 8);
                *reinterpret_cast<bf16x8*>(wqkb + n * 256 + ((g ^ (n & 7)) << 3)) =
                    ld8f_bf(src);
            }
        } else {                    // Wv -> wvb (8192 granules, blocks 2049..2052)
            int base = (blk - 2049) * 2048;
            for (int j = 0; j < 8; ++j) {
                int fg = base + j * 256 + t;
                int slice = fg >> 10, d = fg & 1023;
                int co = d >> 2, g2 = (d & 3) ^ (co & 3);
                *reinterpret_cast<bf16x8*>(wvb + fg * 8) =
                    ld8f_bf(Wv + (size_t)co * 256 + slice * 32 + g2 * 8);
            }
        }
        return;
    }
    __shared__ u16 tile[64][68];
    int b = blk >> 8;
    int r = blk & 255;
    int c0 = (r & 3) * 64;
    int n0 = (r >> 2) * 64;
    const float* xb = x + (size_t)b * 256 * 4096;
    u16* xTb = xT + (size_t)b * 4096 * 256;
    int lc = t >> 4;
    int l4 = (t & 15) * 4;
    #pragma unroll
    for (int p = 0; p < 4; ++p) {
        int c = lc + p * 16;
        float4 v = *reinterpret_cast<const float4*>(xb + (size_t)(c0 + c) * 4096 + n0 + l4);
        tile[c][l4 + 0] = f2bf(v.x); tile[c][l4 + 1] = f2bf(v.y);
        tile[c][l4 + 2] = f2bf(v.z); tile[c][l4 + 3] = f2bf(v.w);
    }
    __syncthreads();
    #pragma unroll
    for (int p = 0; p < 4; ++p) {
        int n = lc + p * 16;
        ushort4 v;
        v.x = tile[l4 + 0][n]; v.y = tile[l4 + 1][n];
        v.z = tile[l4 + 2][n]; v.w = tile[l4 + 3][n];
        int gslot = ((c0 + l4) >> 3) ^ ((n0 + n) & 7);
        *reinterpret_cast<ushort4*>(
            xTb + (size_t)(n0 + n) * 256 + (gslot << 3) + (l4 & 7)) = v;
    }
}

// ---------------------------------------------------------------------------
// Kernel 2 (v9, kept): mega-block fused q/k/v projection. 256 blocks x 512
// threads, n-slab 128, all-LDS staging, 1 block/CU.
// ---------------------------------------------------------------------------
__global__ __launch_bounds__(512, 2) void k_proj(
    const u16* __restrict__ xT, const u16* __restrict__ wqkb,
    const u16* __restrict__ wvb,
    const float* __restrict__ bq, const float* __restrict__ bk,
    const float* __restrict__ bv,
    u16* __restrict__ qt, u16* __restrict__ kt, u16* __restrict__ vt) {
    __shared__ u16 Xs[128 * 256];
    __shared__ u16 Ws[64 * 256];
    __shared__ u16 Wvs[256 * 32];
    int blk = blockIdx.x;
    int b = blk & 7;
    int n0 = (blk >> 3) * 128;
    int t = threadIdx.x;
    int w = t >> 6;
    int lane = t & 63;
    int lo = lane & 15;
    int q = lane >> 4;
    const u16* xTb = xT + (size_t)b * 4096 * 256;

    #pragma unroll
    for (int p = 0; p < 8; ++p)
        g2lds16(xTb + (size_t)n0 * 256 + (p * 512 + t) * 8, &Xs[(p * 512 + w * 64) * 8]);
    #pragma unroll
    for (int p = 0; p < 4; ++p)
        g2lds16(wqkb + (p * 512 + t) * 8, &Ws[(p * 512 + w * 64) * 8]);

    f32x4 accqk[4] = {};
    f32x4 accv[16];
    #pragma unroll
    for (int i = 0; i < 16; ++i) accv[i] = f32x4{0.f, 0.f, 0.f, 0.f};

    int rowA = w * 16 + lo;
    int cw = (w & 3) * 64;
    int nh = (w >> 2) * 64;
    for (int c0 = 0; c0 < 256; c0 += 32) {
        __syncthreads();
        #pragma unroll
        for (int p = 0; p < 2; ++p)
            g2lds16(wvb + (size_t)(c0 >> 5) * 8192 + (p * 512 + t) * 8,
                    &Wvs[(p * 512 + w * 64) * 8]);
        __syncthreads();

        int K = c0 >> 3;
        bf16x8 a = *reinterpret_cast<const bf16x8*>(
            &Xs[(rowA * 32 + ((K + q) ^ (lo & 7))) * 8]);
        #pragma unroll
        for (int ot = 0; ot < 4; ++ot) {
            bf16x8 bb = *reinterpret_cast<const bf16x8*>(
                &Ws[((ot * 16 + lo) * 32 + ((K + q) ^ (lo & 7))) * 8]);
            accqk[ot] = __builtin_amdgcn_mfma_f32_16x16x32_bf16(a, bb, accqk[ot], 0, 0, 0);
        }
        bf16x8 xbf[4];
        #pragma unroll
        for (int nt = 0; nt < 4; ++nt)
            xbf[nt] = *reinterpret_cast<const bf16x8*>(
                &Xs[((nh + nt * 16 + lo) * 32 + ((K + q) ^ (lo & 7))) * 8]);
        #pragma unroll
        for (int ct = 0; ct < 4; ++ct) {
            int co = cw + ct * 16 + lo;
            bf16x8 av = *reinterpret_cast<const bf16x8*>(
                &Wvs[(co * 4 + (q ^ (co & 3))) * 8]);
            #pragma unroll
            for (int nt = 0; nt < 4; ++nt)
                accv[ct * 4 + nt] = __builtin_amdgcn_mfma_f32_16x16x32_bf16(
                    av, xbf[nt], accv[ct * 4 + nt], 0, 0, 0);
        }
    }
    #pragma unroll
    for (int ot = 0; ot < 4; ++ot) {
        float bias = (ot < 2) ? bq[ot * 16 + lo] : bk[(ot - 2) * 16 + lo];
        #pragma unroll
        for (int r = 0; r < 4; ++r) {
            int n = n0 + w * 16 + q * 4 + r;
            float val = accqk[ot][r] + bias;
            if (ot < 2) qt[((size_t)b * 4096 + n) * 32 + ot * 16 + lo] = f2bf(val * LOG2E);
            else        kt[((size_t)b * 4096 + n) * 32 + (ot - 2) * 16 + lo] = f2bf(val);
        }
    }
    #pragma unroll
    for (int ct = 0; ct < 4; ++ct) {
        #pragma unroll
        for (int nt = 0; nt < 4; ++nt) {
            int nt_g = ((n0 + nh) >> 4) + nt;
            #pragma unroll
            for (int r = 0; r < 4; ++r) {
                int co = cw + ct * 16 + q * 4 + r;
                float val = accv[ct * 4 + nt][r] + bv[co];
                vt[(((size_t)b * 256 + nt_g) * 256 + co) * 16 + lo] = f2bf(val);
            }
        }
    }
}

// ---------------------------------------------------------------------------
// Kernel 3 (v12): key-split flash. 512 blocks x 512 threads (8 waves).
// Wave (qw, kh): q-subtile qw*32, key-half kh (2048 keys, 32 steps), ALL 128
// block-channels (v8 per-wave shape -> 116 regs). 2 blocks/CU = 4 waves/SIMD
// at v8's chip-wide exp count (x2, not v11's x4). Key-streams use disjoint
// 32KB LDS halves; O/lsum partials combined through LDS at the end.
// ---------------------------------------------------------------------------
#define FLASH_PV_HALF1(FC0, FC1, Vc_)                                          \
    {                                                                          \
        bf16x8 v0_ = *reinterpret_cast<const bf16x8*>(Vc_ + gslot8);           \
        bf16x8 v1_ = *reinterpret_cast<const bf16x8*>(Vc_ + 512 + gslot8);     \
        bf16x8 v2_ = *reinterpret_cast<const bf16x8*>(Vc_ + 1024 + gslot8);    \
        bf16x8 v3_ = *reinterpret_cast<const bf16x8*>(Vc_ + 1536 + gslot8);    \
        __builtin_amdgcn_s_setprio(1);                                         \
        O0 = MFMA32(v0_, FC0, O0); O1 = MFMA32(v1_, FC0, O1);                  \
        O2 = MFMA32(v2_, FC0, O2); O3 = MFMA32(v3_, FC0, O3);                  \
        __builtin_amdgcn_s_setprio(0);                                         \
        bf16x8 v4_ = *reinterpret_cast<const bf16x8*>(Vc_ + 2048 + gslot8);    \
        bf16x8 v5_ = *reinterpret_cast<const bf16x8*>(Vc_ + 2560 + gslot8);    \
        bf16x8 v6_ = *reinterpret_cast<const bf16x8*>(Vc_ + 3072 + gslot8);    \
        bf16x8 v7_ = *reinterpret_cast<const bf16x8*>(Vc_ + 3584 + gslot8);    \
        __builtin_amdgcn_s_setprio(1);                                         \
        O0 = MFMA32(v4_, FC1, O0); O1 = MFMA32(v5_, FC1, O1);                  \
        O2 = MFMA32(v6_, FC1, O2); O3 = MFMA32(v7_, FC1, O3);                  \
        __builtin_amdgcn_s_setprio(0);                                         \
    }

#define FLASH_PV_HALF2(FC2, FC3, Vc_)                                          \
    {                                                                          \
        bf16x8 v0_ = *reinterpret_cast<const bf16x8*>(Vc_ + 4096 + gslot8);    \
        bf16x8 v1_ = *reinterpret_cast<const bf16x8*>(Vc_ + 4608 + gslot8);    \
        bf16x8 v2_ = *reinterpret_cast<const bf16x8*>(Vc_ + 5120 + gslot8);    \
        bf16x8 v3_ = *reinterpret_cast<const bf16x8*>(Vc_ + 5632 + gslot8);    \
        __builtin_amdgcn_s_setprio(1);                                         \
        O0 = MFMA32(v0_, FC2, O0); O1 = MFMA32(v1_, FC2, O1);                  \
        O2 = MFMA32(v2_, FC2, O2); O3 = MFMA32(v3_, FC2, O3);                  \
        __builtin_amdgcn_s_setprio(0);                                         \
        bf16x8 v4_ = *reinterpret_cast<const bf16x8*>(Vc_ + 6144 + gslot8);    \
        bf16x8 v5_ = *reinterpret_cast<const bf16x8*>(Vc_ + 6656 + gslot8);    \
        bf16x8 v6_ = *reinterpret_cast<const bf16x8*>(Vc_ + 7168 + gslot8);    \
        bf16x8 v7_ = *reinterpret_cast<const bf16x8*>(Vc_ + 7680 + gslot8);    \
        __builtin_amdgcn_s_setprio(1);                                         \
        O0 = MFMA32(v4_, FC3, O0); O1 = MFMA32(v5_, FC3, O1);                  \
        O2 = MFMA32(v6_, FC3, O2); O3 = MFMA32(v7_, FC3, O3);                  \
        __builtin_amdgcn_s_setprio(0);                                         \
    }

// One 64-key step (local step s_ in 0..31). ONE S tile live at a time; single
// K set reloaded after its second use; V(s+1) staged into VDN.
#define FLASH_ITER(S_, VDN)                                                    \
    {                                                                          \
        const int s_ = (S_);                                                   \
        const u16* Vc_ = Vs_my + (size_t)((s_ & 1) * 8192);                    \
        float p_[8];                                                           \
        bf16x8 f0_, f1_;                                                       \
        {                                                                      \
            f32x16 St_ = MFMA32(kC0, qf0, z16);                                \
            St_ = MFMA32(kC1, qf1, St_);                                       \
            _Pragma("unroll")                                                  \
            for (int i_ = 0; i_ < 8; ++i_) {                                   \
                p_[i_] = __builtin_amdgcn_exp2f(St_[i_]); lsum += p_[i_];      \
            }                                                                  \
            f0_ = pack8(p_);                                                   \
            _Pragma("unroll")                                                  \
            for (int i_ = 0; i_ < 8; ++i_) {                                   \
                p_[i_] = __builtin_amdgcn_exp2f(St_[8 + i_]); lsum += p_[i_];  \
            }                                                                  \
            f1_ = pack8(p_);                                                   \
        }                                                                      \
        FLASH_PV_HALF1(f0_, f1_, Vc_)                                          \
        {                                                                      \
            f32x16 St_ = MFMA32(kC2, qf0, z16);                                \
            St_ = MFMA32(kC3, qf1, St_);                                       \
            const u16* kp_ = kbase + (size_t)(((s_ + 1) & 31) * 2048);         \
            kC0 = *reinterpret_cast<const bf16x8*>(kp_);                       \
            kC1 = *reinterpret_cast<const bf16x8*>(kp_ + 16);                  \
            kC2 = *reinterpret_cast<const bf16x8*>(kp_ + 1024);                \
            kC3 = *reinterpret_cast<const bf16x8*>(kp_ + 1040);                \
            const u16* vs_ = vstage + (size_t)(((s_ + 1) & 31)) * 16384;       \
            g2lds16(vs_,        VDN);                                          \
            g2lds16(vs_ + 512,  VDN + 512);                                    \
            g2lds16(vs_ + 1024, VDN + 1024);                                   \
            g2lds16(vs_ + 1536, VDN + 1536);                                   \
            _Pragma("unroll")                                                  \
            for (int i_ = 0; i_ < 8; ++i_) {                                   \
                p_[i_] = __builtin_amdgcn_exp2f(St_[i_]); lsum += p_[i_];      \
            }                                                                  \
            f0_ = pack8(p_);                                                   \
            _Pragma("unroll")                                                  \
            for (int i_ = 0; i_ < 8; ++i_) {                                   \
                p_[i_] = __builtin_amdgcn_exp2f(St_[8 + i_]); lsum += p_[i_];  \
            }                                                                  \
            f1_ = pack8(p_);                                                   \
        }                                                                      \
        FLASH_PV_HALF2(f0_, f1_, Vc_)                                          \
        __syncthreads();                                                       \
    }

__global__ __launch_bounds__(512, 4) void k_flash(
    const u16* __restrict__ qt, const u16* __restrict__ kt,
    const u16* __restrict__ vt, const float* __restrict__ x,
    const float* __restrict__ gamma, float* __restrict__ out) {
    __shared__ u16 Vs[2][2][8192];   // [key-half][buf][16 chunks x 512 u16]
    __shared__ float Ls[4][32];      // kh=1 lsum partials per q-subtile
    int blk = blockIdx.x;
    int b = blk & 7;
    int rest = blk >> 3;
    int m0 = (rest & 31) * 128;
    int ch0 = (rest >> 5) * 128;
    int t = threadIdx.x;
    int w = t >> 6;
    int qw = w & 3;      // q-subtile
    int kh = w >> 2;     // key half
    int lane = t & 63;
    int la = lane & 31;
    int hi = lane >> 5;

    const u16* qtb = qt + (size_t)b * 4096 * 32;
    const u16* ktb = kt + (size_t)b * 4096 * 32;
    const u16* vtb = vt + (size_t)b * 256 * 256 * 16;

    int qw0 = m0 + qw * 32;
    bf16x8 qf0 = *reinterpret_cast<const bf16x8*>(qtb + (size_t)(qw0 + la) * 32 + hi * 8);
    bf16x8 qf1 = *reinterpret_cast<const bf16x8*>(qtb + (size_t)(qw0 + la) * 32 + 16 + hi * 8);

    const u16* kbase = ktb + (size_t)(kh * 2048 + la) * 32 + hi * 8;

    int g = la * 2 + hi;
    int gslot8 = (g ^ (g >> 3)) * 8;   // read-slot swizzle (involution)
    int sg = lane ^ (lane >> 3);       // pre-swizzled staging source granule
    // wave (qw,kh) stages nt chunk kh*128 + s*4 + qw (its 128-ch slice)
    const u16* vstage = vtb + ((size_t)((kh * 128 + qw) * 256) + ch0) * 16 + sg * 8;
    u16* Vs_my = &Vs[kh][0][0];
    u16* vd0 = Vs_my + qw * 2048;          // buf 0
    u16* vd1 = Vs_my + 8192 + qw * 2048;   // buf 1

    f32x16 O0 = {}, O1 = {}, O2 = {}, O3 = {};
    const f32x16 z16 = {};
    float lsum = 0.f;

    bf16x8 kC0, kC1, kC2, kC3;

    // ---- prologue: K(0), stage V(0)->buf0 ----
    kC0 = *reinterpret_cast<const bf16x8*>(kbase);
    kC1 = *reinterpret_cast<const bf16x8*>(kbase + 16);
    kC2 = *reinterpret_cast<const bf16x8*>(kbase + 1024);
    kC3 = *reinterpret_cast<const bf16x8*>(kbase + 1040);
    g2lds16(vstage,        vd0);
    g2lds16(vstage + 512,  vd0 + 512);
    g2lds16(vstage + 1024, vd0 + 1024);
    g2lds16(vstage + 1536, vd0 + 1536);
    __syncthreads();   // V(0) staged (drains vmcnt)

    // ---- main loop: 16 unrolled pairs (local steps 0..31) ----
    for (int ss = 0; ss < 16; ++ss) {
        int s0 = ss * 2;
        FLASH_ITER(s0,     vd1)
        FLASH_ITER(s0 + 1, vd0)
    }

    // ---- per-wave rowsum over its key half ----
    lsum += __shfl_xor(lsum, 32, 64);

    // ---- combine key-half partials via LDS (reuse Vs: 64 KB = 4 x 16 KB) ----
    float* Cmb = (float*)&Vs[0][0][0];
    int cbase = qw * 4096 + lane;
    if (kh == 1) {
        if (lane < 32) Ls[qw][lane] = lsum;
        #pragma unroll
        for (int r = 0; r < 16; ++r) {
            Cmb[cbase + (0 * 16 + r) * 64] = O0[r];
            Cmb[cbase + (1 * 16 + r) * 64] = O1[r];
            Cmb[cbase + (2 * 16 + r) * 64] = O2[r];
            Cmb[cbase + (3 * 16 + r) * 64] = O3[r];
        }
    }
    __syncthreads();
    if (kh == 0) {
        lsum += Ls[qw][la];
        #pragma unroll
        for (int r = 0; r < 16; ++r) {
            O0[r] += Cmb[cbase + (0 * 16 + r) * 64];
            O1[r] += Cmb[cbase + (1 * 16 + r) * 64];
            O2[r] += Cmb[cbase + (2 * 16 + r) * 64];
            O3[r] += Cmb[cbase + (3 * 16 + r) * 64];
        }
        float linv = 1.0f / lsum;
        float gm = gamma[0];
        const float* xb = x + (size_t)b * 256 * 4096;
        float* ob = out + (size_t)b * 256 * 4096;
        int m = m0 + qw * 32 + la;
        #pragma unroll
        for (int r = 0; r < 16; ++r) {
            int crow = (r & 3) + 8 * (r >> 2) + 4 * hi;
            size_t i0 = (size_t)(ch0 + crow) * 4096 + m;
            ob[i0]             = gm * (O0[r] * linv) + xb[i0];
            ob[i0 + 32 * 4096] = gm * (O1[r] * linv) + xb[i0 + 32 * 4096];
            ob[i0 + 64 * 4096] = gm * (O2[r] * linv) + xb[i0 + 64 * 4096];
            ob[i0 + 96 * 4096] = gm * (O3[r] * linv) + xb[i0 + 96 * 4096];
        }
    }
}

// ---------------------------------------------------------------------------
// fp32 I/O. Internal bf16. Workspace: qt 2 + kt 2 + vt 16 = 20 MiB.
// d_out (32 MiB): xT bf16 16 MiB + wqkb 32 KiB + wvb 128 KiB (dead before
// k_flash writes out).
// ---------------------------------------------------------------------------
extern "C" void kernel_launch(void* const* d_in, const int* in_sizes, int n_in,
                              void* d_out, int out_size, void* d_ws, size_t ws_size,
                              hipStream_t stream) {
    const float* x     = (const float*)d_in[0];
    const float* Wq    = (const float*)d_in[1];
    const float* bq    = (const float*)d_in[2];
    const float* Wk    = (const float*)d_in[3];
    const float* bk    = (const float*)d_in[4];
    const float* Wv    = (const float*)d_in[5];
    const float* bv    = (const float*)d_in[6];
    const float* gamma = (const float*)d_in[7];
    float* out = (float*)d_out;

    char* ws = (char*)d_ws;
    u16* xT   = (u16*)d_out;                      // 16 MiB bf16 scratch in d_out
    u16* wqkb = (u16*)d_out + 8388608;            // 32 KiB
    u16* wvb  = (u16*)d_out + 8388608 + 16384;    // 128 KiB
    u16* qt = (u16*)ws;                           //  2 MiB [B,N,32]
    u16* kt = (u16*)(ws + 2097152);               //  2 MiB [B,N,32]
    u16* vt = (u16*)(ws + 2 * 2097152);           // 16 MiB [B,nt,ch,16]

    k_transpose<<<2053, 256, 0, stream>>>(x, Wq, Wk, Wv, xT, wqkb, wvb);
    k_proj<<<256, 512, 0, stream>>>(xT, wqkb, wvb, bq, bk, bv, qt, kt, vt);
    k_flash<<<512, 512, 0, stream>>>(qt, kt, vt, x, gamma, out);
}

// Round 10
// 218.399 us; speedup vs baseline: 1.4850x; 1.4850x over previous
//
#include <hip/hip_runtime.h>
#include <stdint.h>

typedef unsigned short u16;
typedef unsigned int u32;
typedef __bf16 bf16_t;
typedef __bf16 bf16x4 __attribute__((ext_vector_type(4)));
typedef __bf16 bf16x8 __attribute__((ext_vector_type(8)));
typedef float f32x4 __attribute__((ext_vector_type(4)));
typedef float f32x16 __attribute__((ext_vector_type(16)));

#define LOG2E 1.4426950408889634f
#define MFMA32(a, b, c) __builtin_amdgcn_mfma_f32_32x32x16_bf16(a, b, c, 0, 0, 0)

__device__ __forceinline__ u16 f2bf(float f) {
    union { float f; unsigned int u; } v; v.f = f;
    unsigned int r = v.u + 0x7fffu + ((v.u >> 16) & 1u);
    return (u16)(r >> 16);
}

__device__ __forceinline__ bf16x8 ld8f_bf(const float* __restrict__ p) {
    float4 a = *reinterpret_cast<const float4*>(p);
    float4 b = *reinterpret_cast<const float4*>(p + 4);
    bf16x8 r;
    r[0] = (bf16_t)a.x; r[1] = (bf16_t)a.y; r[2] = (bf16_t)a.z; r[3] = (bf16_t)a.w;
    r[4] = (bf16_t)b.x; r[5] = (bf16_t)b.y; r[6] = (bf16_t)b.z; r[7] = (bf16_t)b.w;
    return r;
}

__device__ __forceinline__ u32 cvt_pk_bf16(float a, float b) {
    u32 r;
    asm("v_cvt_pk_bf16_f32 %0, %1, %2" : "=v"(r) : "v"(a), "v"(b));
    return r;
}

__device__ __forceinline__ void plane32_swap(u32& a, u32& b) {
    asm("v_permlane32_swap_b32 %0, %1" : "+v"(a), "+v"(b));
}

// Build PV B-operand fragment (16 keys) from 8 consecutive QK C-regs.
__device__ __forceinline__ bf16x8 pack8(const float* p) {
    u32 c0 = cvt_pk_bf16(p[0], p[1]);
    u32 c1 = cvt_pk_bf16(p[2], p[3]);
    u32 c2 = cvt_pk_bf16(p[4], p[5]);
    u32 c3 = cvt_pk_bf16(p[6], p[7]);
    plane32_swap(c0, c2);
    plane32_swap(c1, c3);
    union { u32 u[4]; bf16x8 v; } f;
    f.u[0] = c0; f.u[1] = c1; f.u[2] = c2; f.u[3] = c3;
    return f.v;
}

// async global->LDS, 16B per lane; LDS dest wave-uniform base + lane*16
__device__ __forceinline__ void g2lds16(const u16* g, u16* l) {
    __builtin_amdgcn_global_load_lds(
        (const __attribute__((address_space(1))) unsigned int*)g,
        (__attribute__((address_space(3))) unsigned int*)l, 16, 0, 0);
}

// ---------------------------------------------------------------------------
// Kernel 1: x[B,C,N] fp32 -> xT[B,N,C] bf16, PRE-SWIZZLED per 16B granule:
// row n, granule g stored at granule slot g^(n&7). Blocks >= 2048 convert
// weights to bf16: wqkb = [64 rows (Wq||Wk)][32 granules swizzled g^(n&7)],
// wvb = 8 slices x 1024 granules (slot d holds Wv[d>>2][slice*32+((d&3)^((d>>2)&3))*8..]).
// ---------------------------------------------------------------------------
__global__ __launch_bounds__(256) void k_transpose(
    const float* __restrict__ x,
    const float* __restrict__ Wq, const float* __restrict__ Wk,
    const float* __restrict__ Wv,
    u16* __restrict__ xT, u16* __restrict__ wqkb, u16* __restrict__ wvb) {
    int blk = blockIdx.x;
    int t = threadIdx.x;
    if (blk >= 2048) {
        if (blk == 2048) {          // Wq||Wk -> wqkb (2048 granules)
            for (int j = 0; j < 8; ++j) {
                int fg = j * 256 + t;
                int n = fg >> 5, g = fg & 31;
                const float* src = (n < 32) ? (Wq + (size_t)n * 256 + g * 8)
                                            : (Wk + (size_t)(n - 32) * 256 + g * 8);
                *reinterpret_cast<bf16x8*>(wqkb + n * 256 + ((g ^ (n & 7)) << 3)) =
                    ld8f_bf(src);
            }
        } else {                    // Wv -> wvb (8192 granules, blocks 2049..2052)
            int base = (blk - 2049) * 2048;
            for (int j = 0; j < 8; ++j) {
                int fg = base + j * 256 + t;
                int slice = fg >> 10, d = fg & 1023;
                int co = d >> 2, g2 = (d & 3) ^ (co & 3);
                *reinterpret_cast<bf16x8*>(wvb + fg * 8) =
                    ld8f_bf(Wv + (size_t)co * 256 + slice * 32 + g2 * 8);
            }
        }
        return;
    }
    __shared__ u16 tile[64][68];
    int b = blk >> 8;
    int r = blk & 255;
    int c0 = (r & 3) * 64;
    int n0 = (r >> 2) * 64;
    const float* xb = x + (size_t)b * 256 * 4096;
    u16* xTb = xT + (size_t)b * 4096 * 256;
    int lc = t >> 4;
    int l4 = (t & 15) * 4;
    #pragma unroll
    for (int p = 0; p < 4; ++p) {
        int c = lc + p * 16;
        float4 v = *reinterpret_cast<const float4*>(xb + (size_t)(c0 + c) * 4096 + n0 + l4);
        tile[c][l4 + 0] = f2bf(v.x); tile[c][l4 + 1] = f2bf(v.y);
        tile[c][l4 + 2] = f2bf(v.z); tile[c][l4 + 3] = f2bf(v.w);
    }
    __syncthreads();
    #pragma unroll
    for (int p = 0; p < 4; ++p) {
        int n = lc + p * 16;
        ushort4 v;
        v.x = tile[l4 + 0][n]; v.y = tile[l4 + 1][n];
        v.z = tile[l4 + 2][n]; v.w = tile[l4 + 3][n];
        int gslot = ((c0 + l4) >> 3) ^ ((n0 + n) & 7);
        *reinterpret_cast<ushort4*>(
            xTb + (size_t)(n0 + n) * 256 + (gslot << 3) + (l4 & 7)) = v;
    }
}

// ---------------------------------------------------------------------------
// Kernel 2 (v9, kept): mega-block fused q/k/v projection. 256 blocks x 512
// threads, n-slab 128, all-LDS staging, 1 block/CU.
// ---------------------------------------------------------------------------
__global__ __launch_bounds__(512, 2) void k_proj(
    const u16* __restrict__ xT, const u16* __restrict__ wqkb,
    const u16* __restrict__ wvb,
    const float* __restrict__ bq, const float* __restrict__ bk,
    const float* __restrict__ bv,
    u16* __restrict__ qt, u16* __restrict__ kt, u16* __restrict__ vt) {
    __shared__ u16 Xs[128 * 256];
    __shared__ u16 Ws[64 * 256];
    __shared__ u16 Wvs[256 * 32];
    int blk = blockIdx.x;
    int b = blk & 7;
    int n0 = (blk >> 3) * 128;
    int t = threadIdx.x;
    int w = t >> 6;
    int lane = t & 63;
    int lo = lane & 15;
    int q = lane >> 4;
    const u16* xTb = xT + (size_t)b * 4096 * 256;

    #pragma unroll
    for (int p = 0; p < 8; ++p)
        g2lds16(xTb + (size_t)n0 * 256 + (p * 512 + t) * 8, &Xs[(p * 512 + w * 64) * 8]);
    #pragma unroll
    for (int p = 0; p < 4; ++p)
        g2lds16(wqkb + (p * 512 + t) * 8, &Ws[(p * 512 + w * 64) * 8]);

    f32x4 accqk[4] = {};
    f32x4 accv[16];
    #pragma unroll
    for (int i = 0; i < 16; ++i) accv[i] = f32x4{0.f, 0.f, 0.f, 0.f};

    int rowA = w * 16 + lo;
    int cw = (w & 3) * 64;
    int nh = (w >> 2) * 64;
    for (int c0 = 0; c0 < 256; c0 += 32) {
        __syncthreads();
        #pragma unroll
        for (int p = 0; p < 2; ++p)
            g2lds16(wvb + (size_t)(c0 >> 5) * 8192 + (p * 512 + t) * 8,
                    &Wvs[(p * 512 + w * 64) * 8]);
        __syncthreads();

        int K = c0 >> 3;
        bf16x8 a = *reinterpret_cast<const bf16x8*>(
            &Xs[(rowA * 32 + ((K + q) ^ (lo & 7))) * 8]);
        #pragma unroll
        for (int ot = 0; ot < 4; ++ot) {
            bf16x8 bb = *reinterpret_cast<const bf16x8*>(
                &Ws[((ot * 16 + lo) * 32 + ((K + q) ^ (lo & 7))) * 8]);
            accqk[ot] = __builtin_amdgcn_mfma_f32_16x16x32_bf16(a, bb, accqk[ot], 0, 0, 0);
        }
        bf16x8 xbf[4];
        #pragma unroll
        for (int nt = 0; nt < 4; ++nt)
            xbf[nt] = *reinterpret_cast<const bf16x8*>(
                &Xs[((nh + nt * 16 + lo) * 32 + ((K + q) ^ (lo & 7))) * 8]);
        #pragma unroll
        for (int ct = 0; ct < 4; ++ct) {
            int co = cw + ct * 16 + lo;
            bf16x8 av = *reinterpret_cast<const bf16x8*>(
                &Wvs[(co * 4 + (q ^ (co & 3))) * 8]);
            #pragma unroll
            for (int nt = 0; nt < 4; ++nt)
                accv[ct * 4 + nt] = __builtin_amdgcn_mfma_f32_16x16x32_bf16(
                    av, xbf[nt], accv[ct * 4 + nt], 0, 0, 0);
        }
    }
    #pragma unroll
    for (int ot = 0; ot < 4; ++ot) {
        float bias = (ot < 2) ? bq[ot * 16 + lo] : bk[(ot - 2) * 16 + lo];
        #pragma unroll
        for (int r = 0; r < 4; ++r) {
            int n = n0 + w * 16 + q * 4 + r;
            float val = accqk[ot][r] + bias;
            if (ot < 2) qt[((size_t)b * 4096 + n) * 32 + ot * 16 + lo] = f2bf(val * LOG2E);
            else        kt[((size_t)b * 4096 + n) * 32 + (ot - 2) * 16 + lo] = f2bf(val);
        }
    }
    #pragma unroll
    for (int ct = 0; ct < 4; ++ct) {
        #pragma unroll
        for (int nt = 0; nt < 4; ++nt) {
            int nt_g = ((n0 + nh) >> 4) + nt;
            #pragma unroll
            for (int r = 0; r < 4; ++r) {
                int co = cw + ct * 16 + q * 4 + r;
                float val = accv[ct * 4 + nt][r] + bv[co];
                vt[(((size_t)b * 256 + nt_g) * 256 + co) * 16 + lo] = f2bf(val);
            }
        }
    }
}

// ---------------------------------------------------------------------------
// Kernel 3 (v13): key-split flash with 4-wave blocks and NO forced reg cap.
// 1024 blocks x 256 thr: block = 64q x 128ch x key-half-split. Wave (qw,kh)
// = 32q x 128ch x 2048 keys (64 steps of 32 keys) — v8's proven wave shape.
// Grid-supplied occupancy: 4096 waves = 4/SIMD if regs<=128 (graceful to
// 3/SIMD at <=170; lb(256,2) keeps cap 256 -> spill-impossible).
// kh partials combined in-block through the V-LDS after the loop.
// ---------------------------------------------------------------------------
#define FLASH_ITER(S_, VDN)                                                    \
    {                                                                          \
        const int s_ = (S_);                                                   \
        f32x16 St_ = MFMA32(kC0, qf0, z16);                                    \
        St_ = MFMA32(kC1, qf1, St_);                                           \
        const u16* kp_ = kbase + (size_t)(((s_ + 1) & 63) * 1024);             \
        kC0 = *reinterpret_cast<const bf16x8*>(kp_);                           \
        kC1 = *reinterpret_cast<const bf16x8*>(kp_ + 16);                      \
        const u16* vs_ = vstage + (size_t)((s_ + 1) & 63) * 8192;              \
        g2lds16(vs_,        VDN);                                              \
        g2lds16(vs_ + 512,  VDN + 512);                                        \
        g2lds16(vs_ + 1024, VDN + 1024);                                       \
        g2lds16(vs_ + 1536, VDN + 1536);                                       \
        const u16* Vc_ = Vs_my + (size_t)((s_ & 1) * 4096);                    \
        float p_[8];                                                           \
        bf16x8 f0_, f1_;                                                       \
        _Pragma("unroll")                                                      \
        for (int i_ = 0; i_ < 8; ++i_) {                                       \
            p_[i_] = __builtin_amdgcn_exp2f(St_[i_]); lsum += p_[i_];          \
        }                                                                      \
        f0_ = pack8(p_);                                                       \
        _Pragma("unroll")                                                      \
        for (int i_ = 0; i_ < 8; ++i_) {                                       \
            p_[i_] = __builtin_amdgcn_exp2f(St_[8 + i_]); lsum += p_[i_];      \
        }                                                                      \
        f1_ = pack8(p_);                                                       \
        {                                                                      \
            bf16x8 v0_ = *reinterpret_cast<const bf16x8*>(Vc_ + gslot8);       \
            bf16x8 v1_ = *reinterpret_cast<const bf16x8*>(Vc_ + 512 + gslot8); \
            bf16x8 v2_ = *reinterpret_cast<const bf16x8*>(Vc_ + 1024 + gslot8);\
            bf16x8 v3_ = *reinterpret_cast<const bf16x8*>(Vc_ + 1536 + gslot8);\
            __builtin_amdgcn_s_setprio(1);                                     \
            O0 = MFMA32(v0_, f0_, O0); O1 = MFMA32(v1_, f0_, O1);              \
            O2 = MFMA32(v2_, f0_, O2); O3 = MFMA32(v3_, f0_, O3);              \
            __builtin_amdgcn_s_setprio(0);                                     \
            bf16x8 v4_ = *reinterpret_cast<const bf16x8*>(Vc_ + 2048 + gslot8);\
            bf16x8 v5_ = *reinterpret_cast<const bf16x8*>(Vc_ + 2560 + gslot8);\
            bf16x8 v6_ = *reinterpret_cast<const bf16x8*>(Vc_ + 3072 + gslot8);\
            bf16x8 v7_ = *reinterpret_cast<const bf16x8*>(Vc_ + 3584 + gslot8);\
            __builtin_amdgcn_s_setprio(1);                                     \
            O0 = MFMA32(v4_, f1_, O0); O1 = MFMA32(v5_, f1_, O1);              \
            O2 = MFMA32(v6_, f1_, O2); O3 = MFMA32(v7_, f1_, O3);              \
            __builtin_amdgcn_s_setprio(0);                                     \
        }                                                                      \
        __syncthreads();                                                       \
    }

__global__ __launch_bounds__(256, 2) void k_flash(
    const u16* __restrict__ qt, const u16* __restrict__ kt,
    const u16* __restrict__ vt, const float* __restrict__ x,
    const float* __restrict__ gamma, float* __restrict__ out) {
    __shared__ u16 Vs[2][2][4096];   // [kh][buf][8 chunks x 512 u16] = 32 KB
    __shared__ float Ls[2][32];      // kh=1 lsum partials per qw
    int blk = blockIdx.x;
    int b = blk & 7;
    int rest = blk >> 3;             // 0..127 = 64 m-tiles x 2 ch
    int m0 = (rest & 63) * 64;
    int ch0 = (rest >> 6) * 128;
    int t = threadIdx.x;
    int w = t >> 6;
    int qw = w & 1;      // q-subtile (32 rows)
    int kh = w >> 1;     // key half
    int lane = t & 63;
    int la = lane & 31;
    int hi = lane >> 5;

    const u16* qtb = qt + (size_t)b * 4096 * 32;
    const u16* ktb = kt + (size_t)b * 4096 * 32;
    const u16* vtb = vt + (size_t)b * 256 * 256 * 16;

    int qw0 = m0 + qw * 32;
    bf16x8 qf0 = *reinterpret_cast<const bf16x8*>(qtb + (size_t)(qw0 + la) * 32 + hi * 8);
    bf16x8 qf1 = *reinterpret_cast<const bf16x8*>(qtb + (size_t)(qw0 + la) * 32 + 16 + hi * 8);

    // K base for this wave's key-half; step stride = 32 keys * 32 ch = 1024 u16
    const u16* kbase = ktb + (size_t)(kh * 2048 + la) * 32 + hi * 8;

    int g = la * 2 + hi;
    int gslot8 = (g ^ (g >> 3)) * 8;   // read-slot swizzle (involution)
    int sg = lane ^ (lane >> 3);       // pre-swizzled staging source granule
    // wave (qw,kh) stages key-granule kg=qw of stream kh (4 ch-chunks):
    // nt(s) = kh*128 + s*2 + qw ; chunk i covers ch0 + i*32
    const u16* vstage = vtb + (((size_t)(kh * 128 + qw) * 256) + ch0) * 16 + sg * 8;
    u16* Vs_my = &Vs[kh][0][0];
    u16* vd0 = Vs_my + qw * 2048;          // buf 0, chunks qw*4..qw*4+3
    u16* vd1 = Vs_my + 4096 + qw * 2048;   // buf 1

    f32x16 O0 = {}, O1 = {}, O2 = {}, O3 = {};
    const f32x16 z16 = {};
    float lsum = 0.f;

    bf16x8 kC0, kC1;

    // ---- prologue: K(0), stage V(0)->buf0 ----
    kC0 = *reinterpret_cast<const bf16x8*>(kbase);
    kC1 = *reinterpret_cast<const bf16x8*>(kbase + 16);
    g2lds16(vstage,        vd0);
    g2lds16(vstage + 512,  vd0 + 512);
    g2lds16(vstage + 1024, vd0 + 1024);
    g2lds16(vstage + 1536, vd0 + 1536);
    __syncthreads();   // V(0) staged (drains vmcnt)

    // ---- main loop: 32 unrolled pairs (steps 0..63, 32 keys each) ----
    for (int ss = 0; ss < 32; ++ss) {
        int s0 = ss * 2;
        FLASH_ITER(s0,     vd1)
        FLASH_ITER(s0 + 1, vd0)
    }

    // ---- per-wave rowsum over its key half ----
    lsum += __shfl_xor(lsum, 32, 64);

    // ---- combine kh partials via LDS (reuse Vs: 32 KB = 8192 f32) ----
    float* Cmb = (float*)&Vs[0][0][0];
    if (kh == 1) {
        if (lane < 32) Ls[qw][lane] = lsum;
        #pragma unroll
        for (int r = 0; r < 16; ++r) {
            Cmb[(r)      * 128 + qw * 64 + lane] = O0[r];
            Cmb[(16 + r) * 128 + qw * 64 + lane] = O1[r];
            Cmb[(32 + r) * 128 + qw * 64 + lane] = O2[r];
            Cmb[(48 + r) * 128 + qw * 64 + lane] = O3[r];
        }
    }
    __syncthreads();
    if (kh == 0) {
        lsum += Ls[qw][la];
        #pragma unroll
        for (int r = 0; r < 16; ++r) {
            O0[r] += Cmb[(r)      * 128 + qw * 64 + lane];
            O1[r] += Cmb[(16 + r) * 128 + qw * 64 + lane];
            O2[r] += Cmb[(32 + r) * 128 + qw * 64 + lane];
            O3[r] += Cmb[(48 + r) * 128 + qw * 64 + lane];
        }
        float linv = 1.0f / lsum;
        float gm = gamma[0];
        const float* xb = x + (size_t)b * 256 * 4096;
        float* ob = out + (size_t)b * 256 * 4096;
        int m = m0 + qw * 32 + la;
        #pragma unroll
        for (int r = 0; r < 16; ++r) {
            int crow = (r & 3) + 8 * (r >> 2) + 4 * hi;
            size_t i0 = (size_t)(ch0 + crow) * 4096 + m;
            ob[i0]             = gm * (O0[r] * linv) + xb[i0];
            ob[i0 + 32 * 4096] = gm * (O1[r] * linv) + xb[i0 + 32 * 4096];
            ob[i0 + 64 * 4096] = gm * (O2[r] * linv) + xb[i0 + 64 * 4096];
            ob[i0 + 96 * 4096] = gm * (O3[r] * linv) + xb[i0 + 96 * 4096];
        }
    }
}

// ---------------------------------------------------------------------------
// fp32 I/O. Internal bf16. Workspace: qt 2 + kt 2 + vt 16 = 20 MiB.
// d_out (32 MiB): xT bf16 16 MiB + wqkb 32 KiB + wvb 128 KiB (dead before
// k_flash writes out).
// ---------------------------------------------------------------------------
extern "C" void kernel_launch(void* const* d_in, const int* in_sizes, int n_in,
                              void* d_out, int out_size, void* d_ws, size_t ws_size,
                              hipStream_t stream) {
    const float* x     = (const float*)d_in[0];
    const float* Wq    = (const float*)d_in[1];
    const float* bq    = (const float*)d_in[2];
    const float* Wk    = (const float*)d_in[3];
    const float* bk    = (const float*)d_in[4];
    const float* Wv    = (const float*)d_in[5];
    const float* bv    = (const float*)d_in[6];
    const float* gamma = (const float*)d_in[7];
    float* out = (float*)d_out;

    char* ws = (char*)d_ws;
    u16* xT   = (u16*)d_out;                      // 16 MiB bf16 scratch in d_out
    u16* wqkb = (u16*)d_out + 8388608;            // 32 KiB
    u16* wvb  = (u16*)d_out + 8388608 + 16384;    // 128 KiB
    u16* qt = (u16*)ws;                           //  2 MiB [B,N,32]
    u16* kt = (u16*)(ws + 2097152);               //  2 MiB [B,N,32]
    u16* vt = (u16*)(ws + 2 * 2097152);           // 16 MiB [B,nt,ch,16]

    k_transpose<<<2053, 256, 0, stream>>>(x, Wq, Wk, Wv, xT, wqkb, wvb);
    k_proj<<<256, 512, 0, stream>>>(xT, wqkb, wvb, bq, bk, bv, qt, kt, vt);
    k_flash<<<1024, 256, 0, stream>>>(qt, kt, vt, x, gamma, out);
}

// Round 11
// 201.908 us; speedup vs baseline: 1.6063x; 1.0817x over previous
//
#include <hip/hip_runtime.h>
#include <stdint.h>

typedef unsigned short u16;
typedef unsigned int u32;
typedef __bf16 bf16_t;
typedef __bf16 bf16x4 __attribute__((ext_vector_type(4)));
typedef __bf16 bf16x8 __attribute__((ext_vector_type(8)));
typedef float f32x4 __attribute__((ext_vector_type(4)));
typedef float f32x16 __attribute__((ext_vector_type(16)));

#define LOG2E 1.4426950408889634f
#define MFMA32(a, b, c) __builtin_amdgcn_mfma_f32_32x32x16_bf16(a, b, c, 0, 0, 0)

__device__ __forceinline__ u16 f2bf(float f) {
    union { float f; unsigned int u; } v; v.f = f;
    unsigned int r = v.u + 0x7fffu + ((v.u >> 16) & 1u);
    return (u16)(r >> 16);
}

__device__ __forceinline__ bf16x8 ld8f_bf(const float* __restrict__ p) {
    float4 a = *reinterpret_cast<const float4*>(p);
    float4 b = *reinterpret_cast<const float4*>(p + 4);
    bf16x8 r;
    r[0] = (bf16_t)a.x; r[1] = (bf16_t)a.y; r[2] = (bf16_t)a.z; r[3] = (bf16_t)a.w;
    r[4] = (bf16_t)b.x; r[5] = (bf16_t)b.y; r[6] = (bf16_t)b.z; r[7] = (bf16_t)b.w;
    return r;
}

__device__ __forceinline__ u32 cvt_pk_bf16(float a, float b) {
    u32 r;
    asm("v_cvt_pk_bf16_f32 %0, %1, %2" : "=v"(r) : "v"(a), "v"(b));
    return r;
}

__device__ __forceinline__ void plane32_swap(u32& a, u32& b) {
    asm("v_permlane32_swap_b32 %0, %1" : "+v"(a), "+v"(b));
}

// Build PV B-operand fragment (16 keys) from 8 consecutive QK C-regs.
__device__ __forceinline__ bf16x8 pack8(const float* p) {
    u32 c0 = cvt_pk_bf16(p[0], p[1]);
    u32 c1 = cvt_pk_bf16(p[2], p[3]);
    u32 c2 = cvt_pk_bf16(p[4], p[5]);
    u32 c3 = cvt_pk_bf16(p[6], p[7]);
    plane32_swap(c0, c2);
    plane32_swap(c1, c3);
    union { u32 u[4]; bf16x8 v; } f;
    f.u[0] = c0; f.u[1] = c1; f.u[2] = c2; f.u[3] = c3;
    return f.v;
}

// async global->LDS, 16B per lane; LDS dest wave-uniform base + lane*16
__device__ __forceinline__ void g2lds16(const u16* g, u16* l) {
    __builtin_amdgcn_global_load_lds(
        (const __attribute__((address_space(1))) unsigned int*)g,
        (__attribute__((address_space(3))) unsigned int*)l, 16, 0, 0);
}

// ---------------------------------------------------------------------------
// Kernel 1: x[B,C,N] fp32 -> xT[B,N,C] bf16, PRE-SWIZZLED per 16B granule:
// row n, granule g stored at granule slot g^(n&7). Blocks >= 2048 convert
// weights to bf16: wqkb = [64 rows (Wq||Wk)][32 granules swizzled g^(n&7)],
// wvb = 8 slices x 1024 granules (slot d holds Wv[d>>2][slice*32+((d&3)^((d>>2)&3))*8..]).
// ---------------------------------------------------------------------------
__global__ __launch_bounds__(256) void k_transpose(
    const float* __restrict__ x,
    const float* __restrict__ Wq, const float* __restrict__ Wk,
    const float* __restrict__ Wv,
    u16* __restrict__ xT, u16* __restrict__ wqkb, u16* __restrict__ wvb) {
    int blk = blockIdx.x;
    int t = threadIdx.x;
    if (blk >= 2048) {
        if (blk == 2048) {          // Wq||Wk -> wqkb (2048 granules)
            for (int j = 0; j < 8; ++j) {
                int fg = j * 256 + t;
                int n = fg >> 5, g = fg & 31;
                const float* src = (n < 32) ? (Wq + (size_t)n * 256 + g * 8)
                                            : (Wk + (size_t)(n - 32) * 256 + g * 8);
                *reinterpret_cast<bf16x8*>(wqkb + n * 256 + ((g ^ (n & 7)) << 3)) =
                    ld8f_bf(src);
            }
        } else {                    // Wv -> wvb (8192 granules, blocks 2049..2052)
            int base = (blk - 2049) * 2048;
            for (int j = 0; j < 8; ++j) {
                int fg = base + j * 256 + t;
                int slice = fg >> 10, d = fg & 1023;
                int co = d >> 2, g2 = (d & 3) ^ (co & 3);
                *reinterpret_cast<bf16x8*>(wvb + fg * 8) =
                    ld8f_bf(Wv + (size_t)co * 256 + slice * 32 + g2 * 8);
            }
        }
        return;
    }
    __shared__ u16 tile[64][68];
    int b = blk >> 8;
    int r = blk & 255;
    int c0 = (r & 3) * 64;
    int n0 = (r >> 2) * 64;
    const float* xb = x + (size_t)b * 256 * 4096;
    u16* xTb = xT + (size_t)b * 4096 * 256;
    int lc = t >> 4;
    int l4 = (t & 15) * 4;
    #pragma unroll
    for (int p = 0; p < 4; ++p) {
        int c = lc + p * 16;
        float4 v = *reinterpret_cast<const float4*>(xb + (size_t)(c0 + c) * 4096 + n0 + l4);
        tile[c][l4 + 0] = f2bf(v.x); tile[c][l4 + 1] = f2bf(v.y);
        tile[c][l4 + 2] = f2bf(v.z); tile[c][l4 + 3] = f2bf(v.w);
    }
    __syncthreads();
    #pragma unroll
    for (int p = 0; p < 4; ++p) {
        int n = lc + p * 16;
        ushort4 v;
        v.x = tile[l4 + 0][n]; v.y = tile[l4 + 1][n];
        v.z = tile[l4 + 2][n]; v.w = tile[l4 + 3][n];
        int gslot = ((c0 + l4) >> 3) ^ ((n0 + n) & 7);
        *reinterpret_cast<ushort4*>(
            xTb + (size_t)(n0 + n) * 256 + (gslot << 3) + (l4 & 7)) = v;
    }
}

// ---------------------------------------------------------------------------
// Kernel 2 (v14): mega-block proj + DOUBLE-BUFFERED Wvs (one barrier per
// c-step instead of two; staging overlaps MFMA). 256 blocks x 512 threads,
// LDS = Xs 64K + Ws 32K + Wvs 2x16K = 128 KB, 1 block/CU.
// ---------------------------------------------------------------------------
__global__ __launch_bounds__(512, 2) void k_proj(
    const u16* __restrict__ xT, const u16* __restrict__ wqkb,
    const u16* __restrict__ wvb,
    const float* __restrict__ bq, const float* __restrict__ bk,
    const float* __restrict__ bv,
    u16* __restrict__ qt, u16* __restrict__ kt, u16* __restrict__ vt) {
    __shared__ u16 Xs[128 * 256];
    __shared__ u16 Ws[64 * 256];
    __shared__ u16 Wvs[2][256 * 32];
    int blk = blockIdx.x;
    int b = blk & 7;
    int n0 = (blk >> 3) * 128;
    int t = threadIdx.x;
    int w = t >> 6;
    int lane = t & 63;
    int lo = lane & 15;
    int q = lane >> 4;
    const u16* xTb = xT + (size_t)b * 4096 * 256;

    // ---- stage Xs, Ws, Wvs[0]: linear async copies ----
    #pragma unroll
    for (int p = 0; p < 8; ++p)
        g2lds16(xTb + (size_t)n0 * 256 + (p * 512 + t) * 8, &Xs[(p * 512 + w * 64) * 8]);
    #pragma unroll
    for (int p = 0; p < 4; ++p)
        g2lds16(wqkb + (p * 512 + t) * 8, &Ws[(p * 512 + w * 64) * 8]);
    #pragma unroll
    for (int p = 0; p < 2; ++p)
        g2lds16(wvb + (p * 512 + t) * 8, &Wvs[0][(p * 512 + w * 64) * 8]);

    f32x4 accqk[4] = {};
    f32x4 accv[16];
    #pragma unroll
    for (int i = 0; i < 16; ++i) accv[i] = f32x4{0.f, 0.f, 0.f, 0.f};

    int rowA = w * 16 + lo;
    int cw = (w & 3) * 64;
    int nh = (w >> 2) * 64;
    __syncthreads();   // all staging done (drains vmcnt)

    for (int s = 0; s < 8; ++s) {
        int c0 = s * 32;
        const u16* Wv_r = &Wvs[s & 1][0];
        u16* Wv_w = &Wvs[(s + 1) & 1][0];
        if (s < 7) {
            #pragma unroll
            for (int p = 0; p < 2; ++p)
                g2lds16(wvb + (size_t)(s + 1) * 8192 + (p * 512 + t) * 8,
                        Wv_w + (p * 512 + w * 64) * 8);
        }
        int K = c0 >> 3;
        bf16x8 a = *reinterpret_cast<const bf16x8*>(
            &Xs[(rowA * 32 + ((K + q) ^ (lo & 7))) * 8]);
        #pragma unroll
        for (int ot = 0; ot < 4; ++ot) {
            bf16x8 bb = *reinterpret_cast<const bf16x8*>(
                &Ws[((ot * 16 + lo) * 32 + ((K + q) ^ (lo & 7))) * 8]);
            accqk[ot] = __builtin_amdgcn_mfma_f32_16x16x32_bf16(a, bb, accqk[ot], 0, 0, 0);
        }
        bf16x8 xbf[4];
        #pragma unroll
        for (int nt = 0; nt < 4; ++nt)
            xbf[nt] = *reinterpret_cast<const bf16x8*>(
                &Xs[((nh + nt * 16 + lo) * 32 + ((K + q) ^ (lo & 7))) * 8]);
        #pragma unroll
        for (int ct = 0; ct < 4; ++ct) {
            int co = cw + ct * 16 + lo;
            bf16x8 av = *reinterpret_cast<const bf16x8*>(
                Wv_r + (co * 4 + (q ^ (co & 3))) * 8);
            #pragma unroll
            for (int nt = 0; nt < 4; ++nt)
                accv[ct * 4 + nt] = __builtin_amdgcn_mfma_f32_16x16x32_bf16(
                    av, xbf[nt], accv[ct * 4 + nt], 0, 0, 0);
        }
        __syncthreads();   // staging into Wv_w complete; reads of Wv_r done
    }
    #pragma unroll
    for (int ot = 0; ot < 4; ++ot) {
        float bias = (ot < 2) ? bq[ot * 16 + lo] : bk[(ot - 2) * 16 + lo];
        #pragma unroll
        for (int r = 0; r < 4; ++r) {
            int n = n0 + w * 16 + q * 4 + r;
            float val = accqk[ot][r] + bias;
            if (ot < 2) qt[((size_t)b * 4096 + n) * 32 + ot * 16 + lo] = f2bf(val * LOG2E);
            else        kt[((size_t)b * 4096 + n) * 32 + (ot - 2) * 16 + lo] = f2bf(val);
        }
    }
    #pragma unroll
    for (int ct = 0; ct < 4; ++ct) {
        #pragma unroll
        for (int nt = 0; nt < 4; ++nt) {
            int nt_g = ((n0 + nh) >> 4) + nt;
            #pragma unroll
            for (int r = 0; r < 4; ++r) {
                int co = cw + ct * 16 + q * 4 + r;
                float val = accv[ct * 4 + nt][r] + bv[co];
                vt[(((size_t)b * 256 + nt_g) * 256 + co) * 16 + lo] = f2bf(val);
            }
        }
    }
}

// ---------------------------------------------------------------------------
// Kernel 3 (v6 verbatim, measured 100.3 us): flash attention, 32x32 MFMA,
// E in registers, V+K staged in LDS (shared by 4 waves), double-buffered,
// global_load_lds prefetch. Granule g at slot g^(g>>3) via pre-swizzled
// global source addresses.
// ---------------------------------------------------------------------------
__global__ __launch_bounds__(256, 2) void k_flash(
    const u16* __restrict__ qt, const u16* __restrict__ kt,
    const u16* __restrict__ vt, const float* __restrict__ x,
    const float* __restrict__ gamma, float* __restrict__ out) {
    __shared__ u16 Vs[2][8192];   // 16 chunks (kc*4+cg) x 512 u16
    __shared__ u16 Ks[2][2048];   // 4 chunks x 512 u16
    int blk = blockIdx.x;
    int b = blk & 7;
    int rest = blk >> 3;
    int m0 = (rest & 31) * 128;
    int ch0 = (rest >> 5) * 128;
    int t = threadIdx.x;
    int w = t >> 6;
    int lane = t & 63;
    int la = lane & 31;
    int hi = lane >> 5;

    const u16* qtb = qt + (size_t)b * 4096 * 32;
    const u16* ktb = kt + (size_t)b * 4096 * 32;
    const u16* vtb = vt + (size_t)b * 256 * 256 * 16;

    int qw0 = m0 + w * 32;
    bf16x8 qf0 = *reinterpret_cast<const bf16x8*>(qtb + (size_t)(qw0 + la) * 32 + hi * 8);
    bf16x8 qf1 = *reinterpret_cast<const bf16x8*>(qtb + (size_t)(qw0 + la) * 32 + 16 + hi * 8);

    int g = la * 2 + hi;
    int gslot8 = (g ^ (g >> 3)) * 8;          // u16 offset of this lane's read slot
    int sg = lane ^ (lane >> 3);              // source granule for staging slot=lane

    const u16* vsrc = vtb + ((size_t)w * 256 + ch0) * 16 + sg * 8;
    const u16* ksrc = ktb + (size_t)((w >> 1) * 32 + (sg >> 1)) * 32 + (w & 1) * 16 + (sg & 1) * 8;
    u16* vdstA = &Vs[0][w * 4 * 512];
    u16* kdstA = &Ks[0][w * 512];
    u16* vdstB = &Vs[1][w * 4 * 512];
    u16* kdstB = &Ks[1][w * 512];

    // prologue: stage step 0 into buffer 0
    #pragma unroll
    for (int i = 0; i < 4; ++i) g2lds16(vsrc + i * 512, vdstA + i * 512);
    g2lds16(ksrc, kdstA);
    vsrc += 16384;
    ksrc += 2048;

    f32x16 O0 = {}, O1 = {}, O2 = {}, O3 = {};
    const f32x16 z16 = {};
    float lsum = 0.f;
    __syncthreads();

    for (int s = 0; s < 64; ++s) {
        const u16* Vc = Vs[s & 1];
        const u16* Kc = Ks[s & 1];
        if (s < 63) {
            u16* vd = (s & 1) ? vdstA : vdstB;
            u16* kd = (s & 1) ? kdstA : kdstB;
            #pragma unroll
            for (int i = 0; i < 4; ++i) g2lds16(vsrc + i * 512, vd + i * 512);
            g2lds16(ksrc, kd);
            vsrc += 16384;
            ksrc += 2048;
        }
        bf16x8 kf00 = *reinterpret_cast<const bf16x8*>(Kc + 0 * 512 + gslot8);
        bf16x8 kf01 = *reinterpret_cast<const bf16x8*>(Kc + 1 * 512 + gslot8);
        bf16x8 kf10 = *reinterpret_cast<const bf16x8*>(Kc + 2 * 512 + gslot8);
        bf16x8 kf11 = *reinterpret_cast<const bf16x8*>(Kc + 3 * 512 + gslot8);
        f32x16 S0 = MFMA32(kf00, qf0, z16);
        S0 = MFMA32(kf01, qf1, S0);
        f32x16 S1 = MFMA32(kf10, qf0, z16);
        S1 = MFMA32(kf11, qf1, S1);
        float p0[16];
        #pragma unroll
        for (int i = 0; i < 16; ++i) {
            p0[i] = __builtin_amdgcn_exp2f(S0[i]);
            lsum += p0[i];
        }
        bf16x8 fA = pack8(p0);
        bf16x8 fB = pack8(p0 + 8);
        {
            bf16x8 v0 = *reinterpret_cast<const bf16x8*>(Vc + 0 * 512 + gslot8);
            bf16x8 v1 = *reinterpret_cast<const bf16x8*>(Vc + 1 * 512 + gslot8);
            bf16x8 v2 = *reinterpret_cast<const bf16x8*>(Vc + 2 * 512 + gslot8);
            bf16x8 v3 = *reinterpret_cast<const bf16x8*>(Vc + 3 * 512 + gslot8);
            O0 = MFMA32(v0, fA, O0);
            O1 = MFMA32(v1, fA, O1);
            O2 = MFMA32(v2, fA, O2);
            O3 = MFMA32(v3, fA, O3);
            bf16x8 v4 = *reinterpret_cast<const bf16x8*>(Vc + 4 * 512 + gslot8);
            bf16x8 v5 = *reinterpret_cast<const bf16x8*>(Vc + 5 * 512 + gslot8);
            bf16x8 v6 = *reinterpret_cast<const bf16x8*>(Vc + 6 * 512 + gslot8);
            bf16x8 v7 = *reinterpret_cast<const bf16x8*>(Vc + 7 * 512 + gslot8);
            O0 = MFMA32(v4, fB, O0);
            O1 = MFMA32(v5, fB, O1);
            O2 = MFMA32(v6, fB, O2);
            O3 = MFMA32(v7, fB, O3);
        }
        float p1[16];
        #pragma unroll
        for (int i = 0; i < 16; ++i) {
            p1[i] = __builtin_amdgcn_exp2f(S1[i]);
            lsum += p1[i];
        }
        bf16x8 fC = pack8(p1);
        bf16x8 fD = pack8(p1 + 8);
        {
            bf16x8 v0 = *reinterpret_cast<const bf16x8*>(Vc + 8 * 512 + gslot8);
            bf16x8 v1 = *reinterpret_cast<const bf16x8*>(Vc + 9 * 512 + gslot8);
            bf16x8 v2 = *reinterpret_cast<const bf16x8*>(Vc + 10 * 512 + gslot8);
            bf16x8 v3 = *reinterpret_cast<const bf16x8*>(Vc + 11 * 512 + gslot8);
            O0 = MFMA32(v0, fC, O0);
            O1 = MFMA32(v1, fC, O1);
            O2 = MFMA32(v2, fC, O2);
            O3 = MFMA32(v3, fC, O3);
            bf16x8 v4 = *reinterpret_cast<const bf16x8*>(Vc + 12 * 512 + gslot8);
            bf16x8 v5 = *reinterpret_cast<const bf16x8*>(Vc + 13 * 512 + gslot8);
            bf16x8 v6 = *reinterpret_cast<const bf16x8*>(Vc + 14 * 512 + gslot8);
            bf16x8 v7 = *reinterpret_cast<const bf16x8*>(Vc + 15 * 512 + gslot8);
            O0 = MFMA32(v4, fD, O0);
            O1 = MFMA32(v5, fD, O1);
            O2 = MFMA32(v6, fD, O2);
            O3 = MFMA32(v7, fD, O3);
        }
        __syncthreads();
    }

    lsum += __shfl_xor(lsum, 32, 64);
    float linv = 1.0f / lsum;
    float gm = gamma[0];
    const float* xb = x + (size_t)b * 256 * 4096;
    float* ob = out + (size_t)b * 256 * 4096;
    int m = m0 + w * 32 + la;
    #pragma unroll
    for (int r = 0; r < 16; ++r) {
        int crow = (r & 3) + 8 * (r >> 2) + 4 * hi;
        size_t i0 = (size_t)(ch0 + crow) * 4096 + m;
        ob[i0]             = gm * (O0[r] * linv) + xb[i0];
        ob[i0 + 32 * 4096] = gm * (O1[r] * linv) + xb[i0 + 32 * 4096];
        ob[i0 + 64 * 4096] = gm * (O2[r] * linv) + xb[i0 + 64 * 4096];
        ob[i0 + 96 * 4096] = gm * (O3[r] * linv) + xb[i0 + 96 * 4096];
    }
}

// ---------------------------------------------------------------------------
// fp32 I/O. Internal bf16. Workspace: qt 2 + kt 2 + vt 16 = 20 MiB.
// d_out (32 MiB): xT bf16 16 MiB + wqkb 32 KiB + wvb 128 KiB (dead before
// k_flash writes out).
// ---------------------------------------------------------------------------
extern "C" void kernel_launch(void* const* d_in, const int* in_sizes, int n_in,
                              void* d_out, int out_size, void* d_ws, size_t ws_size,
                              hipStream_t stream) {
    const float* x     = (const float*)d_in[0];
    const float* Wq    = (const float*)d_in[1];
    const float* bq    = (const float*)d_in[2];
    const float* Wk    = (const float*)d_in[3];
    const float* bk    = (const float*)d_in[4];
    const float* Wv    = (const float*)d_in[5];
    const float* bv    = (const float*)d_in[6];
    const float* gamma = (const float*)d_in[7];
    float* out = (float*)d_out;

    char* ws = (char*)d_ws;
    u16* xT   = (u16*)d_out;                      // 16 MiB bf16 scratch in d_out
    u16* wqkb = (u16*)d_out + 8388608;            // 32 KiB
    u16* wvb  = (u16*)d_out + 8388608 + 16384;    // 128 KiB
    u16* qt = (u16*)ws;                           //  2 MiB [B,N,32]
    u16* kt = (u16*)(ws + 2097152);               //  2 MiB [B,N,32]
    u16* vt = (u16*)(ws + 2 * 2097152);           // 16 MiB [B,nt,ch,16]

    k_transpose<<<2053, 256, 0, stream>>>(x, Wq, Wk, Wv, xT, wqkb, wvb);
    k_proj<<<256, 512, 0, stream>>>(xT, wqkb, wvb, bq, bk, bv, qt, kt, vt);
    k_flash<<<512, 256, 0, stream>>>(qt, kt, vt, x, gamma, out);
}